// Round 8
// baseline (313.926 us; speedup 1.0000x reference)
//
#include <hip/hip_runtime.h>

#define PI_F 3.14159265358979323846f

// ws layout (bytes):
//   0        : trig table — f32 cosphi[1024], sinphi[1024], costh[512],
//              sinth[512] = 12288 B (written by trig_kernel, read by bin)
//   24576    : maxz — u32 maxraw[3*32] then maxdiff[3] (zeroed by trig blk 0)
//   32768    : packed hist u8: 3 planes × 32 hists × 262144 bins = 24 MB
//   25198592 : bucket regions: 4096 bin-blocks × 24640 B each
//              (64 B header: u16 off[25]; 24576 B data: 12288 u16 in-band ids
//               segmented by bucket = plane*8 + band64)  -> ws end ≈ 126.2 MB
#define MAXZ_OFF_B   24576
#define HIST_OFF_B   32768
#define BUCK_OFF_B   25198592
#define REGION_U16   12320          // region stride in u16 units (24640 B)

// Correctly-rounded a/20000 via Markstein refinement (bit-exact RN).
__device__ inline float div20000(float a) {
    const float r = 1.0f / 20000.0f;
    float q0 = a * r;
    float e = fmaf(-20000.0f, q0, a);
    return fmaf(e, r, q0);
}

__device__ inline int bin1(float v) {
    float f = rintf(div20000(v + 10000.0f) * 512.0f);
    return (int)fminf(fmaxf(f, 0.0f), 511.0f);
}

// Pass 0: compute the 1024 phi + 512 theta sin/cos pairs ONCE. Identical FP
// expressions to the original -> bit-identical values (verified absmax 0).
// Block 0 also zeroes maxz + out.
__global__ __launch_bounds__(256) void trig_kernel(
    float* __restrict__ tbl, unsigned* __restrict__ maxz,
    float* __restrict__ out) {
    const int t = threadIdx.x + blockIdx.x * 256;
    if (blockIdx.x == 0) {
        if (threadIdx.x < 128) maxz[threadIdx.x] = 0u;
        if (threadIdx.x == 128) out[0] = 0.0f;
    }
    if (t < 1024) {
        float fj = (float)t;
        float phi = PI_F * ((2.0f * fj) / 1023.0f - 1.0f);
        tbl[t] = cosf(phi);
        tbl[1024 + t] = sinf(phi);
    } else {
        int i = t - 1024;                       // < 512
        float fi = (float)i;
        float theta = -PI_F * (fi / 511.0f - 0.5f);
        tbl[2048 + i] = cosf(theta);
        tbl[2560 + i] = sinf(theta);
    }
}

// Pass 1: round-6 structure (verified 72 µs), with __launch_bounds__(256,6):
// VGPR was 88 -> only 5 waves/SIMD (20 waves/CU, 5 blocks/CU) while LDS
// (25.6 KB) allows 6 blocks/CU. Forcing the allocator to <=85 VGPR unlocks
// the 6th resident block (+20% waves for latency hiding) — bin is
// latency-bound (36% VALU, 23% HBM, no pipe near roofline).
// 4096 blocks = (xcd[0:2], i4[3:9], hh[10:11]), 4 rows/block, XCD-pinned.
// Bucket-sort of 4096 points × 3 planes into 24 (plane, 64-row band)
// segments; 8× replicated rank counters; LDS-staged coalesced copy-out.
// item = [bucket:5][rep:3][rank:9][id:15]. Counts exact.
__global__ __launch_bounds__(256, 6) void bin_kernel(
    const float* __restrict__ pred, const float* __restrict__ gt,
    const float* __restrict__ tbl, unsigned short* __restrict__ buck) {
    __shared__ unsigned cnt[192];               // 24 buckets × 8 replicas
    __shared__ unsigned bsum[24];
    __shared__ unsigned off[25];
    __shared__ __align__(16) unsigned short sdata[12288];
    const int tid = threadIdx.x, wg = blockIdx.x;
    const unsigned rep = (unsigned)(tid & 7);
    const int xcd = wg & 7, i4 = (wg >> 3) & 127, hh = wg >> 10;
    const int h = (hh << 3) | xcd;
    if (tid < 192) cnt[tid] = 0u;
    const float4 cp4 = *(const float4*)&tbl[tid << 2];          // cos phi
    const float4 sp4 = *(const float4*)&tbl[1024 + (tid << 2)]; // sin phi
    const float4 ct4 = *(const float4*)&tbl[2048 + (i4 << 2)];  // cos theta
    const float4 st4 = *(const float4*)&tbl[2560 + (i4 << 2)];  // sin theta
    __syncthreads();
    const float* img = ((h >> 4) ? gt : pred) + ((h & 15) << 19);
    unsigned items[48];
    #pragma unroll
    for (int r = 0; r < 4; ++r) {
        const int i = i4 * 4 + r;
        const float4 d4 = *(const float4*)(img + (i << 10) + (tid << 2));
        const float ct = (&ct4.x)[r], st = (&st4.x)[r];
        #pragma unroll
        for (int k = 0; k < 4; ++k) {
            float d = (&d4.x)[k];
            float aA = (&cp4.x)[k] * ct;        // identical op order to r3/r5
            float aB = (&sp4.x)[k] * ct;
            float A = (d * aA) * 1000.0f;
            float B = (d * aB) * 1000.0f;
            float C = (d * (-st)) * 1000.0f;
            int iA = bin1(A), iB = bin1(B), iC = bin1(C);
            // plane0: y=iB,x=iA; plane1: y=iC,x=iA; plane2: y=iC,x=iB
            unsigned f0 = ((unsigned)iB << 9) | (unsigned)iA;   // 18-bit y*512+x
            unsigned f1 = ((unsigned)iC << 9) | (unsigned)iA;
            unsigned f2 = ((unsigned)iC << 9) | (unsigned)iB;
            unsigned b0 = f0 >> 15;                             // band64 of y
            unsigned b1 = 8u + (f1 >> 15);
            unsigned b2 = 16u + (f2 >> 15);
            unsigned r0 = atomicAdd(&cnt[(b0 << 3) | rep], 1u);
            unsigned r1 = atomicAdd(&cnt[(b1 << 3) | rep], 1u);
            unsigned r2 = atomicAdd(&cnt[(b2 << 3) | rep], 1u);
            const int base = (r * 4 + k) * 3;
            items[base + 0] = (b0 << 27) | (rep << 24) | (r0 << 15) | (f0 & 32767u);
            items[base + 1] = (b1 << 27) | (rep << 24) | (r1 << 15) | (f1 & 32767u);
            items[base + 2] = (b2 << 27) | (rep << 24) | (r2 << 15) | (f2 & 32767u);
        }
    }
    __syncthreads();
    if (tid < 24) {
        unsigned s = 0;
        #pragma unroll
        for (int r = 0; r < 8; ++r) {
            unsigned t = cnt[(tid << 3) | r];
            cnt[(tid << 3) | r] = s;
            s += t;
        }
        bsum[tid] = s;
    }
    __syncthreads();
    if (tid == 0) {
        unsigned s = 0;
        #pragma unroll
        for (int b = 0; b < 24; ++b) { off[b] = s; s += bsum[b]; }
        off[24] = s;                            // == 12288
    }
    __syncthreads();
    if (tid < 24) {
        unsigned o = off[tid];
        #pragma unroll
        for (int r = 0; r < 8; ++r) cnt[(tid << 3) | r] += o;
    }
    __syncthreads();
    #pragma unroll
    for (int t = 0; t < 48; ++t) {
        const unsigned it = items[t];
        const unsigned slot = ((it >> 27) << 3) | ((it >> 24) & 7u);
        sdata[cnt[slot] + ((it >> 15) & 511u)] = (unsigned short)(it & 32767u);
    }
    __syncthreads();
    unsigned short* regG = buck + (size_t)wg * REGION_U16;
    if (tid < 25) regG[tid] = (unsigned short)off[tid];
    const uint4* s4p = (const uint4*)sdata;
    uint4* g4 = (uint4*)(regG + 32);            // data after 64 B header
    #pragma unroll
    for (int c = 0; c < 6; ++c) g4[(c << 8) + tid] = s4p[(c << 8) + tid];
}

// Pass 2: round-6 version VERBATIM (best measured; the round-7 wave-uniform
// collapse taxed every quad for a hot path that isn't the makespan, -5 µs).
// WG = (plane, h, band); 1024 threads, 2 blocks/CU = 32 waves/CU.
// blockIdx bits: [0:2]=xcd==h&7 (L2 pin), [3:4]=h>>3, [5:9]=X (LPT order).
__global__ __launch_bounds__(1024, 8) void scan_kernel(
    const unsigned short* __restrict__ buck, unsigned* __restrict__ hp,
    unsigned* __restrict__ maxraw) {
    __shared__ unsigned lh[16384];              // 64 rows × 512 bins, u16×2
    __shared__ unsigned s4[16];
    const int tid = threadIdx.x, wg = blockIdx.x;
    const int xcd = wg & 7, hhi = (wg >> 3) & 3;
    const int X = wg >> 5;                      // 0..23
    const int pair = X / 6, idx6 = X % 6;
    const int plane = idx6 >> 1;
    const int band = (idx6 & 1) ? (4 + pair) : (3 - pair);
    const int h = (hhi << 3) | xcd;
    const int bucket = plane * 8 + band;

    #pragma unroll
    for (int k = 0; k < 4; ++k)
        *(uint4*)&lh[(k << 12) + (tid << 2)] = make_uint4(0, 0, 0, 0);
    __syncthreads();

    const int wid = tid >> 6, lane = tid & 63;
    for (int i4 = wid; i4 < 128; i4 += 16) {
        const unsigned short* reg =
            buck + (size_t)(xcd | (i4 << 3) | (hhi << 10)) * REGION_U16;
        const int lo = reg[bucket], hi = reg[bucket + 1];
        const unsigned short* data = reg + 32;
        int a = (lo + 7) & ~7;                  // first 16B-aligned index
        if (a > hi) a = hi;
        const int head = a - lo;                // <= 7
        if (lane < head) {
            const unsigned id = data[lo + lane];
            atomicAdd(&lh[id >> 1], 1u << ((id & 1u) << 4));
        }
        const int nv = (hi - a) >> 3;           // full uint4 groups
        for (int v = lane; v < nv; v += 64) {
            const uint4 w = *(const uint4*)&data[a + (v << 3)];
            #pragma unroll
            for (int q = 0; q < 4; ++q) {
                const unsigned u = (&w.x)[q];
                const unsigned idl = u & 65535u, idh = u >> 16;
                atomicAdd(&lh[idl >> 1], 1u << ((idl & 1u) << 4));
                atomicAdd(&lh[idh >> 1], 1u << ((idh & 1u) << 4));
            }
        }
        const int tail = (hi - a) & 7;          // <= 7
        if (lane < tail) {
            const unsigned id = data[a + (nv << 3) + lane];
            atomicAdd(&lh[id >> 1], 1u << ((id & 1u) << 4));
        }
    }
    __syncthreads();

    // pack to u8 (sat 255; downstream clamps at 100) + raw band max
    unsigned m = 0;
    unsigned* gout = hp + ((plane * 32 + h) << 16) + (band << 13);
    #pragma unroll
    for (int k = 0; k < 8; ++k) {
        int w = (k << 10) + tid;
        unsigned v0 = lh[2 * w], v1 = lh[2 * w + 1];
        unsigned c0 = v0 & 65535u, c1 = v0 >> 16;
        unsigned c2 = v1 & 65535u, c3 = v1 >> 16;
        m = max(max(m, max(c0, c1)), max(c2, c3));
        gout[w] = min(c0, 255u) | (min(c1, 255u) << 8) |
                  (min(c2, 255u) << 16) | (min(c3, 255u) << 24);
    }
    #pragma unroll
    for (int o = 32; o; o >>= 1) m = max(m, (unsigned)__shfl_down((int)m, o));
    if ((tid & 63) == 0) s4[tid >> 6] = m;
    __syncthreads();
    if (tid == 0) {
        #pragma unroll
        for (int k = 1; k < 16; ++k) m = max(m, s4[k]);
        atomicMax(&maxraw[plane * 32 + h], m);
    }
}

__device__ inline float blockMaxF(float v) {
    #pragma unroll
    for (int o = 32; o; o >>= 1) v = fmaxf(v, __shfl_down(v, o));
    __shared__ float s[4];
    if ((threadIdx.x & 63) == 0) s[threadIdx.x >> 6] = v;
    __syncthreads();
    if (threadIdx.x == 0) v = fmaxf(fmaxf(s[0], s[1]), fmaxf(s[2], s[3]));
    return v;
}

__device__ inline float blockSumF(float v) {
    #pragma unroll
    for (int o = 32; o; o >>= 1) v += __shfl_down(v, o);
    __shared__ float s[4];
    if ((threadIdx.x & 63) == 0) s[threadIdx.x >> 6] = v;
    __syncthreads();
    if (threadIdx.x == 0) v = (s[0] + s[1]) + (s[2] + s[3]);
    return v;
}

// 768 blocks = 3 planes × 16 b × 16 chunks; uint4 loads. nP/nG are
// block-uniform, so min(v,100)/n over the 256 byte values is precomputed
// into 256-entry LDS tables (one divide per thread, once) — bit-identical
// values, replaces 128 divides/thread with LDS lookups.
__global__ void maxdiff_kernel(const unsigned* __restrict__ hp,
                               const unsigned* __restrict__ maxraw,
                               unsigned* __restrict__ maxdiff) {
    __shared__ float tP[256], tG[256];
    int blk = blockIdx.x;
    int b = blk & 15, chunk = (blk >> 4) & 15, plane = blk >> 8;
    const unsigned* P = hp + ((plane * 32 + b) << 16) + (chunk << 12);
    const unsigned* G = P + (16 << 16);
    float nP = fminf((float)maxraw[plane * 32 + b], 100.0f);
    float nG = fminf((float)maxraw[plane * 32 + 16 + b], 100.0f);
    const int tid = threadIdx.x;
    tP[tid] = fminf((float)tid, 100.0f) / nP;
    tG[tid] = fminf((float)tid, 100.0f) / nG;
    __syncthreads();
    float m = 0.0f;
    #pragma unroll
    for (int k = 0; k < 4; ++k) {
        uint4 wp = *(const uint4*)&P[(k << 10) + (tid << 2)];
        uint4 wg = *(const uint4*)&G[(k << 10) + (tid << 2)];
        #pragma unroll
        for (int w = 0; w < 4; ++w) {
            unsigned up = (&wp.x)[w], ug = (&wg.x)[w];
            #pragma unroll
            for (int s = 0; s < 32; s += 8) {
                float pn = tP[(up >> s) & 255u];
                float gn = tG[(ug >> s) & 255u];
                m = fmaxf(m, fabsf(pn - gn));
            }
        }
    }
    m = blockMaxF(m);
    if (threadIdx.x == 0) atomicMax(&maxdiff[plane], __float_as_uint(m));
}

// Accumulates directly into out[0] (pre-zeroed by trig block 0):
// blocksum/2^22 is an exact power-of-2 scale, then one atomicAdd per block.
__global__ void loss_kernel(const unsigned* __restrict__ hp,
                            const unsigned* __restrict__ maxraw,
                            const unsigned* __restrict__ maxdiff,
                            float* __restrict__ out) {
    __shared__ float tP[256], tG[256];
    int blk = blockIdx.x;
    int b = blk & 15, chunk = (blk >> 4) & 15, plane = blk >> 8;
    const unsigned* P = hp + ((plane * 32 + b) << 16) + (chunk << 12);
    const unsigned* G = P + (16 << 16);
    float c = 0.2f * __uint_as_float(maxdiff[plane]);
    float nP = fminf((float)maxraw[plane * 32 + b], 100.0f);
    float nG = fminf((float)maxraw[plane * 32 + 16 + b], 100.0f);
    const int tid = threadIdx.x;
    tP[tid] = fminf((float)tid, 100.0f) / nP;
    tG[tid] = fminf((float)tid, 100.0f) / nG;
    __syncthreads();
    float acc = 0.0f;
    #pragma unroll
    for (int k = 0; k < 4; ++k) {
        uint4 wp = *(const uint4*)&P[(k << 10) + (tid << 2)];
        uint4 wg = *(const uint4*)&G[(k << 10) + (tid << 2)];
        #pragma unroll
        for (int w = 0; w < 4; ++w) {
            unsigned up = (&wp.x)[w], ug = (&wg.x)[w];
            #pragma unroll
            for (int s = 0; s < 32; s += 8) {
                float pn = tP[(up >> s) & 255u];
                float gn = tG[(ug >> s) & 255u];
                float d = fabsf(pn - gn);
                acc += (d <= c) ? d : (d * d + c * c) / (2.0f * c);
            }
        }
    }
    acc = blockSumF(acc);
    if (threadIdx.x == 0) atomicAdd(out, acc / 4194304.0f);
}

extern "C" void kernel_launch(void* const* d_in, const int* in_sizes, int n_in,
                              void* d_out, int out_size, void* d_ws, size_t ws_size,
                              hipStream_t stream) {
    const float* pred = (const float*)d_in[0];
    const float* gt   = (const float*)d_in[1];
    float* out        = (float*)d_out;
    char* ws          = (char*)d_ws;

    float* tbl        = (float*)ws;
    unsigned* maxz    = (unsigned*)(ws + MAXZ_OFF_B);
    unsigned* maxraw  = maxz;
    unsigned* maxdiff = maxz + 96;
    unsigned* hp      = (unsigned*)(ws + HIST_OFF_B);
    unsigned short* buck = (unsigned short*)(ws + BUCK_OFF_B);

    trig_kernel<<<6, 256, 0, stream>>>(tbl, maxz, out);
    bin_kernel<<<4096, 256, 0, stream>>>(pred, gt, tbl, buck);
    scan_kernel<<<768, 1024, 0, stream>>>(buck, hp, maxraw);
    maxdiff_kernel<<<768, 256, 0, stream>>>(hp, maxraw, maxdiff);
    loss_kernel<<<768, 256, 0, stream>>>(hp, maxraw, maxdiff, out);
}

// Round 9
// 187.475 us; speedup vs baseline: 1.6745x; 1.6745x over previous
//
#include <hip/hip_runtime.h>

#define PI_F 3.14159265358979323846f

// ws layout (bytes):
//   0        : trig table — f32 cosphi[1024], sinphi[1024], costh[512],
//              sinth[512] = 12288 B (written by trig_kernel, read by bin)
//   24576    : maxz — u32 maxraw[3*32] then maxdiff[3] (zeroed by trig blk 0)
//   32768    : packed hist u8: 3 planes × 32 hists × 262144 bins = 24 MB
//   25198592 : bucket regions: 4096 bin-blocks × 24640 B each
//              (64 B header: u16 off[25]; 24576 B data: 12288 u16 in-band ids
//               segmented by bucket = plane*8 + band64)  -> ws end ≈ 126.2 MB
#define MAXZ_OFF_B   24576
#define HIST_OFF_B   32768
#define BUCK_OFF_B   25198592
#define REGION_U16   12320          // region stride in u16 units (24640 B)

// Correctly-rounded a/20000 via Markstein refinement (bit-exact RN).
__device__ inline float div20000(float a) {
    const float r = 1.0f / 20000.0f;
    float q0 = a * r;
    float e = fmaf(-20000.0f, q0, a);
    return fmaf(e, r, q0);
}

__device__ inline int bin1(float v) {
    float f = rintf(div20000(v + 10000.0f) * 512.0f);
    return (int)fminf(fmaxf(f, 0.0f), 511.0f);
}

// Pass 0: compute the 1024 phi + 512 theta sin/cos pairs ONCE. Identical FP
// expressions to the original -> bit-identical values (verified absmax 0).
// Block 0 also zeroes maxz + out.
__global__ __launch_bounds__(256) void trig_kernel(
    float* __restrict__ tbl, unsigned* __restrict__ maxz,
    float* __restrict__ out) {
    const int t = threadIdx.x + blockIdx.x * 256;
    if (blockIdx.x == 0) {
        if (threadIdx.x < 128) maxz[threadIdx.x] = 0u;
        if (threadIdx.x == 128) out[0] = 0.0f;
    }
    if (t < 1024) {
        float fj = (float)t;
        float phi = PI_F * ((2.0f * fj) / 1023.0f - 1.0f);
        tbl[t] = cosf(phi);
        tbl[1024 + t] = sinf(phi);
    } else {
        int i = t - 1024;                       // < 512
        float fi = (float)i;
        float theta = -PI_F * (fi / 511.0f - 0.5f);
        tbl[2048 + i] = cosf(theta);
        tbl[2560 + i] = sinf(theta);
    }
}

// Pass 1: DUAL-PASS bucket sort — eliminates the items[48] register array
// that capped occupancy at 5 blocks/CU (VGPR 88). Round-8 showed forcing
// occupancy via __launch_bounds__(256,6) makes the allocator spill the whole
// array to scratch (450 MB of traffic, 2.3x slower); instead we remove the
// need for it: keep the 4 input float4s live (16 VGPR) and RECOMPUTE the bin
// math in the scatter pass. Ranks come from pass-B atomicAdd returns.
//  * pass A counts only: needs just iB (plane-0 band) and iC (planes 1&2
//    band) — no iA. Buckets 8+x and 16+x have IDENTICAL counts (both keyed
//    on iC>>6), so pass A counts plane-1 only; prefix phase copies the
//    replica partials for buckets 16..23 (one extra barrier).
//  * pass B recomputes f0/f1/f2 (same inputs, same op order -> bit-identical
//    bins) and scatters via 3 rank atomics per point.
// Counts exact, ranks nondeterministic -> downstream bit-identical.
// 4096 blocks = (xcd[0:2], i4[3:9], hh[10:11]), XCD-pinned (wg&7==h&7).
__global__ __launch_bounds__(256) void bin_kernel(
    const float* __restrict__ pred, const float* __restrict__ gt,
    const float* __restrict__ tbl, unsigned short* __restrict__ buck) {
    __shared__ unsigned cnt[192];               // 24 buckets × 8 replicas
    __shared__ unsigned bsum[24];
    __shared__ unsigned off[25];
    __shared__ __align__(16) unsigned short sdata[12288];
    const int tid = threadIdx.x, wg = blockIdx.x;
    const unsigned rep = (unsigned)(tid & 7);
    const int xcd = wg & 7, i4 = (wg >> 3) & 127, hh = wg >> 10;
    const int h = (hh << 3) | xcd;
    if (tid < 192) cnt[tid] = 0u;
    const float4 cp4 = *(const float4*)&tbl[tid << 2];          // cos phi
    const float4 sp4 = *(const float4*)&tbl[1024 + (tid << 2)]; // sin phi
    const float4 ct4 = *(const float4*)&tbl[2048 + (i4 << 2)];  // cos theta
    const float4 st4 = *(const float4*)&tbl[2560 + (i4 << 2)];  // sin theta
    __syncthreads();
    const float* img = ((h >> 4) ? gt : pred) + ((h & 15) << 19);
    // load all 4 rows up-front; kept live across both passes (16 VGPR)
    float4 d4s[4];
    #pragma unroll
    for (int r = 0; r < 4; ++r)
        d4s[r] = *(const float4*)(img + ((i4 * 4 + r) << 10) + (tid << 2));

    // ---- PASS A: count (iB, iC only; plane-1 counts stand in for plane-2)
    #pragma unroll
    for (int r = 0; r < 4; ++r) {
        const float ct = (&ct4.x)[r], st = (&st4.x)[r];
        #pragma unroll
        for (int k = 0; k < 4; ++k) {
            float d = (&d4s[r].x)[k];
            float aB = (&sp4.x)[k] * ct;        // identical op order
            float B = (d * aB) * 1000.0f;
            float C = (d * (-st)) * 1000.0f;
            int iB = bin1(B), iC = bin1(C);
            atomicAdd(&cnt[((unsigned)(iB >> 6) << 3) | rep], 1u);
            atomicAdd(&cnt[((8u + (unsigned)(iC >> 6)) << 3) | rep], 1u);
        }
    }
    __syncthreads();
    // replica exclusive-prefix in place for buckets 0..15
    if (tid < 16) {
        unsigned s = 0;
        #pragma unroll
        for (int r = 0; r < 8; ++r) {
            unsigned t = cnt[(tid << 3) | r];
            cnt[(tid << 3) | r] = s;
            s += t;
        }
        bsum[tid] = s;
    }
    __syncthreads();
    // buckets 16..23 mirror 8..15 (identical counts, keyed on iC>>6)
    if (tid >= 16 && tid < 24) {
        #pragma unroll
        for (int r = 0; r < 8; ++r)
            cnt[(tid << 3) | r] = cnt[((tid - 8) << 3) | r];
        bsum[tid] = bsum[tid - 8];
    }
    __syncthreads();
    if (tid == 0) {
        unsigned s = 0;
        #pragma unroll
        for (int b = 0; b < 24; ++b) { off[b] = s; s += bsum[b]; }
        off[24] = s;                            // == 12288
    }
    __syncthreads();
    if (tid < 24) {
        unsigned o = off[tid];
        #pragma unroll
        for (int r = 0; r < 8; ++r) cnt[(tid << 3) | r] += o;
    }
    __syncthreads();

    // ---- PASS B: recompute + rank-scatter into LDS staging
    #pragma unroll
    for (int r = 0; r < 4; ++r) {
        const float ct = (&ct4.x)[r], st = (&st4.x)[r];
        #pragma unroll
        for (int k = 0; k < 4; ++k) {
            float d = (&d4s[r].x)[k];
            float aA = (&cp4.x)[k] * ct;        // identical op order to r3/r5
            float aB = (&sp4.x)[k] * ct;
            float A = (d * aA) * 1000.0f;
            float B = (d * aB) * 1000.0f;
            float C = (d * (-st)) * 1000.0f;
            int iA = bin1(A), iB = bin1(B), iC = bin1(C);
            // plane0: y=iB,x=iA; plane1: y=iC,x=iA; plane2: y=iC,x=iB
            unsigned f0 = ((unsigned)iB << 9) | (unsigned)iA;
            unsigned f1 = ((unsigned)iC << 9) | (unsigned)iA;
            unsigned f2 = ((unsigned)iC << 9) | (unsigned)iB;
            unsigned b0 = f0 >> 15;             // iB>>6
            unsigned bc = f1 >> 15;             // iC>>6
            unsigned p0 = atomicAdd(&cnt[(b0 << 3) | rep], 1u);
            sdata[p0] = (unsigned short)(f0 & 32767u);
            unsigned p1 = atomicAdd(&cnt[((8u + bc) << 3) | rep], 1u);
            sdata[p1] = (unsigned short)(f1 & 32767u);
            unsigned p2 = atomicAdd(&cnt[((16u + bc) << 3) | rep], 1u);
            sdata[p2] = (unsigned short)(f2 & 32767u);
        }
    }
    __syncthreads();
    unsigned short* regG = buck + (size_t)wg * REGION_U16;
    if (tid < 25) regG[tid] = (unsigned short)off[tid];
    // coalesced copy-out: 12288 u16 = 1536 uint4 = 6 per thread exactly
    const uint4* s4p = (const uint4*)sdata;
    uint4* g4 = (uint4*)(regG + 32);            // data after 64 B header
    #pragma unroll
    for (int c = 0; c < 6; ++c) g4[(c << 8) + tid] = s4p[(c << 8) + tid];
}

// Pass 2: round-6 version VERBATIM (best measured).
// WG = (plane, h, band); 1024 threads, 2 blocks/CU = 32 waves/CU.
// blockIdx bits: [0:2]=xcd==h&7 (L2 pin), [3:4]=h>>3, [5:9]=X (LPT order).
__global__ __launch_bounds__(1024, 8) void scan_kernel(
    const unsigned short* __restrict__ buck, unsigned* __restrict__ hp,
    unsigned* __restrict__ maxraw) {
    __shared__ unsigned lh[16384];              // 64 rows × 512 bins, u16×2
    __shared__ unsigned s4[16];
    const int tid = threadIdx.x, wg = blockIdx.x;
    const int xcd = wg & 7, hhi = (wg >> 3) & 3;
    const int X = wg >> 5;                      // 0..23
    const int pair = X / 6, idx6 = X % 6;
    const int plane = idx6 >> 1;
    const int band = (idx6 & 1) ? (4 + pair) : (3 - pair);
    const int h = (hhi << 3) | xcd;
    const int bucket = plane * 8 + band;

    #pragma unroll
    for (int k = 0; k < 4; ++k)
        *(uint4*)&lh[(k << 12) + (tid << 2)] = make_uint4(0, 0, 0, 0);
    __syncthreads();

    const int wid = tid >> 6, lane = tid & 63;
    for (int i4 = wid; i4 < 128; i4 += 16) {
        const unsigned short* reg =
            buck + (size_t)(xcd | (i4 << 3) | (hhi << 10)) * REGION_U16;
        const int lo = reg[bucket], hi = reg[bucket + 1];
        const unsigned short* data = reg + 32;
        int a = (lo + 7) & ~7;                  // first 16B-aligned index
        if (a > hi) a = hi;
        const int head = a - lo;                // <= 7
        if (lane < head) {
            const unsigned id = data[lo + lane];
            atomicAdd(&lh[id >> 1], 1u << ((id & 1u) << 4));
        }
        const int nv = (hi - a) >> 3;           // full uint4 groups
        for (int v = lane; v < nv; v += 64) {
            const uint4 w = *(const uint4*)&data[a + (v << 3)];
            #pragma unroll
            for (int q = 0; q < 4; ++q) {
                const unsigned u = (&w.x)[q];
                const unsigned idl = u & 65535u, idh = u >> 16;
                atomicAdd(&lh[idl >> 1], 1u << ((idl & 1u) << 4));
                atomicAdd(&lh[idh >> 1], 1u << ((idh & 1u) << 4));
            }
        }
        const int tail = (hi - a) & 7;          // <= 7
        if (lane < tail) {
            const unsigned id = data[a + (nv << 3) + lane];
            atomicAdd(&lh[id >> 1], 1u << ((id & 1u) << 4));
        }
    }
    __syncthreads();

    // pack to u8 (sat 255; downstream clamps at 100) + raw band max
    unsigned m = 0;
    unsigned* gout = hp + ((plane * 32 + h) << 16) + (band << 13);
    #pragma unroll
    for (int k = 0; k < 8; ++k) {
        int w = (k << 10) + tid;
        unsigned v0 = lh[2 * w], v1 = lh[2 * w + 1];
        unsigned c0 = v0 & 65535u, c1 = v0 >> 16;
        unsigned c2 = v1 & 65535u, c3 = v1 >> 16;
        m = max(max(m, max(c0, c1)), max(c2, c3));
        gout[w] = min(c0, 255u) | (min(c1, 255u) << 8) |
                  (min(c2, 255u) << 16) | (min(c3, 255u) << 24);
    }
    #pragma unroll
    for (int o = 32; o; o >>= 1) m = max(m, (unsigned)__shfl_down((int)m, o));
    if ((tid & 63) == 0) s4[tid >> 6] = m;
    __syncthreads();
    if (tid == 0) {
        #pragma unroll
        for (int k = 1; k < 16; ++k) m = max(m, s4[k]);
        atomicMax(&maxraw[plane * 32 + h], m);
    }
}

__device__ inline float blockMaxF(float v) {
    #pragma unroll
    for (int o = 32; o; o >>= 1) v = fmaxf(v, __shfl_down(v, o));
    __shared__ float s[4];
    if ((threadIdx.x & 63) == 0) s[threadIdx.x >> 6] = v;
    __syncthreads();
    if (threadIdx.x == 0) v = fmaxf(fmaxf(s[0], s[1]), fmaxf(s[2], s[3]));
    return v;
}

__device__ inline float blockSumF(float v) {
    #pragma unroll
    for (int o = 32; o; o >>= 1) v += __shfl_down(v, o);
    __shared__ float s[4];
    if ((threadIdx.x & 63) == 0) s[threadIdx.x >> 6] = v;
    __syncthreads();
    if (threadIdx.x == 0) v = (s[0] + s[1]) + (s[2] + s[3]);
    return v;
}

// 768 blocks = 3 planes × 16 b × 16 chunks; uint4 loads. nP/nG are
// block-uniform, so min(v,100)/n over the 256 byte values is precomputed
// into 256-entry LDS tables (bit-identical values).
__global__ void maxdiff_kernel(const unsigned* __restrict__ hp,
                               const unsigned* __restrict__ maxraw,
                               unsigned* __restrict__ maxdiff) {
    __shared__ float tP[256], tG[256];
    int blk = blockIdx.x;
    int b = blk & 15, chunk = (blk >> 4) & 15, plane = blk >> 8;
    const unsigned* P = hp + ((plane * 32 + b) << 16) + (chunk << 12);
    const unsigned* G = P + (16 << 16);
    float nP = fminf((float)maxraw[plane * 32 + b], 100.0f);
    float nG = fminf((float)maxraw[plane * 32 + 16 + b], 100.0f);
    const int tid = threadIdx.x;
    tP[tid] = fminf((float)tid, 100.0f) / nP;
    tG[tid] = fminf((float)tid, 100.0f) / nG;
    __syncthreads();
    float m = 0.0f;
    #pragma unroll
    for (int k = 0; k < 4; ++k) {
        uint4 wp = *(const uint4*)&P[(k << 10) + (tid << 2)];
        uint4 wg = *(const uint4*)&G[(k << 10) + (tid << 2)];
        #pragma unroll
        for (int w = 0; w < 4; ++w) {
            unsigned up = (&wp.x)[w], ug = (&wg.x)[w];
            #pragma unroll
            for (int s = 0; s < 32; s += 8) {
                float pn = tP[(up >> s) & 255u];
                float gn = tG[(ug >> s) & 255u];
                m = fmaxf(m, fabsf(pn - gn));
            }
        }
    }
    m = blockMaxF(m);
    if (threadIdx.x == 0) atomicMax(&maxdiff[plane], __float_as_uint(m));
}

// Accumulates directly into out[0] (pre-zeroed by trig block 0):
// blocksum/2^22 is an exact power-of-2 scale, then one atomicAdd per block.
__global__ void loss_kernel(const unsigned* __restrict__ hp,
                            const unsigned* __restrict__ maxraw,
                            const unsigned* __restrict__ maxdiff,
                            float* __restrict__ out) {
    __shared__ float tP[256], tG[256];
    int blk = blockIdx.x;
    int b = blk & 15, chunk = (blk >> 4) & 15, plane = blk >> 8;
    const unsigned* P = hp + ((plane * 32 + b) << 16) + (chunk << 12);
    const unsigned* G = P + (16 << 16);
    float c = 0.2f * __uint_as_float(maxdiff[plane]);
    float nP = fminf((float)maxraw[plane * 32 + b], 100.0f);
    float nG = fminf((float)maxraw[plane * 32 + 16 + b], 100.0f);
    const int tid = threadIdx.x;
    tP[tid] = fminf((float)tid, 100.0f) / nP;
    tG[tid] = fminf((float)tid, 100.0f) / nG;
    __syncthreads();
    float acc = 0.0f;
    #pragma unroll
    for (int k = 0; k < 4; ++k) {
        uint4 wp = *(const uint4*)&P[(k << 10) + (tid << 2)];
        uint4 wg = *(const uint4*)&G[(k << 10) + (tid << 2)];
        #pragma unroll
        for (int w = 0; w < 4; ++w) {
            unsigned up = (&wp.x)[w], ug = (&wg.x)[w];
            #pragma unroll
            for (int s = 0; s < 32; s += 8) {
                float pn = tP[(up >> s) & 255u];
                float gn = tG[(ug >> s) & 255u];
                float d = fabsf(pn - gn);
                acc += (d <= c) ? d : (d * d + c * c) / (2.0f * c);
            }
        }
    }
    acc = blockSumF(acc);
    if (threadIdx.x == 0) atomicAdd(out, acc / 4194304.0f);
}

extern "C" void kernel_launch(void* const* d_in, const int* in_sizes, int n_in,
                              void* d_out, int out_size, void* d_ws, size_t ws_size,
                              hipStream_t stream) {
    const float* pred = (const float*)d_in[0];
    const float* gt   = (const float*)d_in[1];
    float* out        = (float*)d_out;
    char* ws          = (char*)d_ws;

    float* tbl        = (float*)ws;
    unsigned* maxz    = (unsigned*)(ws + MAXZ_OFF_B);
    unsigned* maxraw  = maxz;
    unsigned* maxdiff = maxz + 96;
    unsigned* hp      = (unsigned*)(ws + HIST_OFF_B);
    unsigned short* buck = (unsigned short*)(ws + BUCK_OFF_B);

    trig_kernel<<<6, 256, 0, stream>>>(tbl, maxz, out);
    bin_kernel<<<4096, 256, 0, stream>>>(pred, gt, tbl, buck);
    scan_kernel<<<768, 1024, 0, stream>>>(buck, hp, maxraw);
    maxdiff_kernel<<<768, 256, 0, stream>>>(hp, maxraw, maxdiff);
    loss_kernel<<<768, 256, 0, stream>>>(hp, maxraw, maxdiff, out);
}

// Round 11
// 184.810 us; speedup vs baseline: 1.6986x; 1.0144x over previous
//
#include <hip/hip_runtime.h>

#define PI_F 3.14159265358979323846f

// ws layout (bytes):
//   0        : trig table — f32 cosphi[1024], sinphi[1024], costh[512],
//              sinth[512] = 12288 B (written by trig_kernel, read by bin)
//   24576    : maxz — u32 maxraw[3*32] then maxdiff[3] (zeroed by trig blk 0)
//   32768    : packed hist u8: 3 planes × 32 hists × 262144 bins = 24 MB
//   25198592 : bucket regions: 4096 bin-blocks × 24640 B each
//              (64 B header: u16 off[25]; 24576 B data: 12288 u16 in-band ids
//               segmented by bucket = plane*8 + band64)  -> ws end ≈ 126.2 MB
#define MAXZ_OFF_B   24576
#define HIST_OFF_B   32768
#define BUCK_OFF_B   25198592
#define REGION_U16   12320          // region stride in u16 units (24640 B)

// Correctly-rounded a/20000 via Markstein refinement (bit-exact RN).
__device__ inline float div20000(float a) {
    const float r = 1.0f / 20000.0f;
    float q0 = a * r;
    float e = fmaf(-20000.0f, q0, a);
    return fmaf(e, r, q0);
}

__device__ inline int bin1(float v) {
    float f = rintf(div20000(v + 10000.0f) * 512.0f);
    return (int)fminf(fmaxf(f, 0.0f), 511.0f);
}

// Pass 0: compute the 1024 phi + 512 theta sin/cos pairs ONCE. Identical FP
// expressions to the original -> bit-identical values (verified absmax 0).
// Block 0 also zeroes maxz + out.
__global__ __launch_bounds__(256) void trig_kernel(
    float* __restrict__ tbl, unsigned* __restrict__ maxz,
    float* __restrict__ out) {
    const int t = threadIdx.x + blockIdx.x * 256;
    if (blockIdx.x == 0) {
        if (threadIdx.x < 128) maxz[threadIdx.x] = 0u;
        if (threadIdx.x == 128) out[0] = 0.0f;
    }
    if (t < 1024) {
        float fj = (float)t;
        float phi = PI_F * ((2.0f * fj) / 1023.0f - 1.0f);
        tbl[t] = cosf(phi);
        tbl[1024 + t] = sinf(phi);
    } else {
        int i = t - 1024;                       // < 512
        float fi = (float)i;
        float theta = -PI_F * (fi / 511.0f - 0.5f);
        tbl[2048 + i] = cosf(theta);
        tbl[2560 + i] = sinf(theta);
    }
}

// Pass 1: round-9 VERBATIM (verified 52 µs, VGPR 40, occupancy 48%).
// DUAL-PASS bucket sort: pass A counts (iB/iC only; plane-1 counts mirror
// plane-2), pass B recomputes bins (same op order -> bit-identical) and
// rank-scatters via atomicAdd returns. No items[] register array.
// 4096 blocks = (xcd[0:2], i4[3:9], hh[10:11]), XCD-pinned (wg&7==h&7).
__global__ __launch_bounds__(256) void bin_kernel(
    const float* __restrict__ pred, const float* __restrict__ gt,
    const float* __restrict__ tbl, unsigned short* __restrict__ buck) {
    __shared__ unsigned cnt[192];               // 24 buckets × 8 replicas
    __shared__ unsigned bsum[24];
    __shared__ unsigned off[25];
    __shared__ __align__(16) unsigned short sdata[12288];
    const int tid = threadIdx.x, wg = blockIdx.x;
    const unsigned rep = (unsigned)(tid & 7);
    const int xcd = wg & 7, i4 = (wg >> 3) & 127, hh = wg >> 10;
    const int h = (hh << 3) | xcd;
    if (tid < 192) cnt[tid] = 0u;
    const float4 cp4 = *(const float4*)&tbl[tid << 2];          // cos phi
    const float4 sp4 = *(const float4*)&tbl[1024 + (tid << 2)]; // sin phi
    const float4 ct4 = *(const float4*)&tbl[2048 + (i4 << 2)];  // cos theta
    const float4 st4 = *(const float4*)&tbl[2560 + (i4 << 2)];  // sin theta
    __syncthreads();
    const float* img = ((h >> 4) ? gt : pred) + ((h & 15) << 19);
    // load all 4 rows up-front; kept live across both passes (16 VGPR)
    float4 d4s[4];
    #pragma unroll
    for (int r = 0; r < 4; ++r)
        d4s[r] = *(const float4*)(img + ((i4 * 4 + r) << 10) + (tid << 2));

    // ---- PASS A: count (iB, iC only; plane-1 counts stand in for plane-2)
    #pragma unroll
    for (int r = 0; r < 4; ++r) {
        const float ct = (&ct4.x)[r], st = (&st4.x)[r];
        #pragma unroll
        for (int k = 0; k < 4; ++k) {
            float d = (&d4s[r].x)[k];
            float aB = (&sp4.x)[k] * ct;        // identical op order
            float B = (d * aB) * 1000.0f;
            float C = (d * (-st)) * 1000.0f;
            int iB = bin1(B), iC = bin1(C);
            atomicAdd(&cnt[((unsigned)(iB >> 6) << 3) | rep], 1u);
            atomicAdd(&cnt[((8u + (unsigned)(iC >> 6)) << 3) | rep], 1u);
        }
    }
    __syncthreads();
    // replica exclusive-prefix in place for buckets 0..15
    if (tid < 16) {
        unsigned s = 0;
        #pragma unroll
        for (int r = 0; r < 8; ++r) {
            unsigned t = cnt[(tid << 3) | r];
            cnt[(tid << 3) | r] = s;
            s += t;
        }
        bsum[tid] = s;
    }
    __syncthreads();
    // buckets 16..23 mirror 8..15 (identical counts, keyed on iC>>6)
    if (tid >= 16 && tid < 24) {
        #pragma unroll
        for (int r = 0; r < 8; ++r)
            cnt[(tid << 3) | r] = cnt[((tid - 8) << 3) | r];
        bsum[tid] = bsum[tid - 8];
    }
    __syncthreads();
    if (tid == 0) {
        unsigned s = 0;
        #pragma unroll
        for (int b = 0; b < 24; ++b) { off[b] = s; s += bsum[b]; }
        off[24] = s;                            // == 12288
    }
    __syncthreads();
    if (tid < 24) {
        unsigned o = off[tid];
        #pragma unroll
        for (int r = 0; r < 8; ++r) cnt[(tid << 3) | r] += o;
    }
    __syncthreads();

    // ---- PASS B: recompute + rank-scatter into LDS staging
    #pragma unroll
    for (int r = 0; r < 4; ++r) {
        const float ct = (&ct4.x)[r], st = (&st4.x)[r];
        #pragma unroll
        for (int k = 0; k < 4; ++k) {
            float d = (&d4s[r].x)[k];
            float aA = (&cp4.x)[k] * ct;        // identical op order to r3/r5
            float aB = (&sp4.x)[k] * ct;
            float A = (d * aA) * 1000.0f;
            float B = (d * aB) * 1000.0f;
            float C = (d * (-st)) * 1000.0f;
            int iA = bin1(A), iB = bin1(B), iC = bin1(C);
            // plane0: y=iB,x=iA; plane1: y=iC,x=iA; plane2: y=iC,x=iB
            unsigned f0 = ((unsigned)iB << 9) | (unsigned)iA;
            unsigned f1 = ((unsigned)iC << 9) | (unsigned)iA;
            unsigned f2 = ((unsigned)iC << 9) | (unsigned)iB;
            unsigned b0 = f0 >> 15;             // iB>>6
            unsigned bc = f1 >> 15;             // iC>>6
            unsigned p0 = atomicAdd(&cnt[(b0 << 3) | rep], 1u);
            sdata[p0] = (unsigned short)(f0 & 32767u);
            unsigned p1 = atomicAdd(&cnt[((8u + bc) << 3) | rep], 1u);
            sdata[p1] = (unsigned short)(f1 & 32767u);
            unsigned p2 = atomicAdd(&cnt[((16u + bc) << 3) | rep], 1u);
            sdata[p2] = (unsigned short)(f2 & 32767u);
        }
    }
    __syncthreads();
    unsigned short* regG = buck + (size_t)wg * REGION_U16;
    if (tid < 25) regG[tid] = (unsigned short)off[tid];
    // coalesced copy-out: 12288 u16 = 1536 uint4 = 6 per thread exactly
    const uint4* s4p = (const uint4*)sdata;
    uint4* g4 = (uint4*)(regG + 32);            // data after 64 B header
    #pragma unroll
    for (int c = 0; c < 6; ++c) g4[(c << 8) + tid] = s4p[(c << 8) + tid];
}

// Pass 2: round-6 structure with HEADER HOISTING (round-10 retry).
// ROUND-10 BUGFIX: header layout is off[0..24] stored explicitly, so
// lo = reg[bucket], hi = reg[bucket+1] (round 10 wrongly used the
// round-4 implicit-zero convention reg[bucket-1]/reg[bucket] -> every
// block scanned the PREVIOUS bucket's segment).
// Theory unchanged: each wave's 8 regions were a serial 2-deep dependent
// chain (header load ~200-900 cyc -> segment load -> atomics); hoisting all
// 16 header loads up-front makes the 8 chains independent so segment loads
// overlap atomic phases. Pure load reorder of immutable data -> identical
// counts, bit-identical hists.
// WG = (plane, h, band); 1024 threads, 2 blocks/CU = 32 waves/CU.
// blockIdx bits: [0:2]=xcd==h&7 (L2 pin), [3:4]=h>>3, [5:9]=X (LPT order).
__global__ __launch_bounds__(1024, 8) void scan_kernel(
    const unsigned short* __restrict__ buck, unsigned* __restrict__ hp,
    unsigned* __restrict__ maxraw) {
    __shared__ unsigned lh[16384];              // 64 rows × 512 bins, u16×2
    __shared__ unsigned s4[16];
    const int tid = threadIdx.x, wg = blockIdx.x;
    const int xcd = wg & 7, hhi = (wg >> 3) & 3;
    const int X = wg >> 5;                      // 0..23
    const int pair = X / 6, idx6 = X % 6;
    const int plane = idx6 >> 1;
    const int band = (idx6 & 1) ? (4 + pair) : (3 - pair);
    const int h = (hhi << 3) | xcd;
    const int bucket = plane * 8 + band;

    #pragma unroll
    for (int k = 0; k < 4; ++k)
        *(uint4*)&lh[(k << 12) + (tid << 2)] = make_uint4(0, 0, 0, 0);
    __syncthreads();

    const int wid = tid >> 6, lane = tid & 63;
    // hoist all 8 region headers (statically-indexed unrolled registers);
    // header word layout matches the bin writer: reg[b] == off[b], b=0..24.
    int lo[8], hi[8];
    #pragma unroll
    for (int j = 0; j < 8; ++j) {
        const unsigned short* reg = buck +
            (size_t)(xcd | ((wid + (j << 4)) << 3) | (hhi << 10)) * REGION_U16;
        lo[j] = reg[bucket];
        hi[j] = reg[bucket + 1];
    }
    #pragma unroll
    for (int j = 0; j < 8; ++j) {
        const unsigned short* data = buck +
            (size_t)(xcd | ((wid + (j << 4)) << 3) | (hhi << 10)) * REGION_U16
            + 32;
        int a = (lo[j] + 7) & ~7;               // first 16B-aligned index
        if (a > hi[j]) a = hi[j];
        const int head = a - lo[j];             // <= 7
        if (lane < head) {
            const unsigned id = data[lo[j] + lane];
            atomicAdd(&lh[id >> 1], 1u << ((id & 1u) << 4));
        }
        const int nv = (hi[j] - a) >> 3;        // full uint4 groups
        for (int v = lane; v < nv; v += 64) {
            const uint4 w = *(const uint4*)&data[a + (v << 3)];
            #pragma unroll
            for (int q = 0; q < 4; ++q) {
                const unsigned u = (&w.x)[q];
                const unsigned idl = u & 65535u, idh = u >> 16;
                atomicAdd(&lh[idl >> 1], 1u << ((idl & 1u) << 4));
                atomicAdd(&lh[idh >> 1], 1u << ((idh & 1u) << 4));
            }
        }
        const int tail = (hi[j] - a) & 7;       // <= 7
        if (lane < tail) {
            const unsigned id = data[a + (nv << 3) + lane];
            atomicAdd(&lh[id >> 1], 1u << ((id & 1u) << 4));
        }
    }
    __syncthreads();

    // pack to u8 (sat 255; downstream clamps at 100) + raw band max
    unsigned m = 0;
    unsigned* gout = hp + ((plane * 32 + h) << 16) + (band << 13);
    #pragma unroll
    for (int k = 0; k < 8; ++k) {
        int w = (k << 10) + tid;
        unsigned v0 = lh[2 * w], v1 = lh[2 * w + 1];
        unsigned c0 = v0 & 65535u, c1 = v0 >> 16;
        unsigned c2 = v1 & 65535u, c3 = v1 >> 16;
        m = max(max(m, max(c0, c1)), max(c2, c3));
        gout[w] = min(c0, 255u) | (min(c1, 255u) << 8) |
                  (min(c2, 255u) << 16) | (min(c3, 255u) << 24);
    }
    #pragma unroll
    for (int o = 32; o; o >>= 1) m = max(m, (unsigned)__shfl_down((int)m, o));
    if ((tid & 63) == 0) s4[tid >> 6] = m;
    __syncthreads();
    if (tid == 0) {
        #pragma unroll
        for (int k = 1; k < 16; ++k) m = max(m, s4[k]);
        atomicMax(&maxraw[plane * 32 + h], m);
    }
}

__device__ inline float blockMaxF(float v) {
    #pragma unroll
    for (int o = 32; o; o >>= 1) v = fmaxf(v, __shfl_down(v, o));
    __shared__ float s[4];
    if ((threadIdx.x & 63) == 0) s[threadIdx.x >> 6] = v;
    __syncthreads();
    if (threadIdx.x == 0) v = fmaxf(fmaxf(s[0], s[1]), fmaxf(s[2], s[3]));
    return v;
}

__device__ inline float blockSumF(float v) {
    #pragma unroll
    for (int o = 32; o; o >>= 1) v += __shfl_down(v, o);
    __shared__ float s[4];
    if ((threadIdx.x & 63) == 0) s[threadIdx.x >> 6] = v;
    __syncthreads();
    if (threadIdx.x == 0) v = (s[0] + s[1]) + (s[2] + s[3]);
    return v;
}

// 768 blocks = 3 planes × 16 b × 16 chunks; uint4 loads. nP/nG are
// block-uniform, so min(v,100)/n over the 256 byte values is precomputed
// into 256-entry LDS tables (bit-identical values).
__global__ void maxdiff_kernel(const unsigned* __restrict__ hp,
                               const unsigned* __restrict__ maxraw,
                               unsigned* __restrict__ maxdiff) {
    __shared__ float tP[256], tG[256];
    int blk = blockIdx.x;
    int b = blk & 15, chunk = (blk >> 4) & 15, plane = blk >> 8;
    const unsigned* P = hp + ((plane * 32 + b) << 16) + (chunk << 12);
    const unsigned* G = P + (16 << 16);
    float nP = fminf((float)maxraw[plane * 32 + b], 100.0f);
    float nG = fminf((float)maxraw[plane * 32 + 16 + b], 100.0f);
    const int tid = threadIdx.x;
    tP[tid] = fminf((float)tid, 100.0f) / nP;
    tG[tid] = fminf((float)tid, 100.0f) / nG;
    __syncthreads();
    float m = 0.0f;
    #pragma unroll
    for (int k = 0; k < 4; ++k) {
        uint4 wp = *(const uint4*)&P[(k << 10) + (tid << 2)];
        uint4 wg = *(const uint4*)&G[(k << 10) + (tid << 2)];
        #pragma unroll
        for (int w = 0; w < 4; ++w) {
            unsigned up = (&wp.x)[w], ug = (&wg.x)[w];
            #pragma unroll
            for (int s = 0; s < 32; s += 8) {
                float pn = tP[(up >> s) & 255u];
                float gn = tG[(ug >> s) & 255u];
                m = fmaxf(m, fabsf(pn - gn));
            }
        }
    }
    m = blockMaxF(m);
    if (threadIdx.x == 0) atomicMax(&maxdiff[plane], __float_as_uint(m));
}

// Accumulates directly into out[0] (pre-zeroed by trig block 0):
// blocksum/2^22 is an exact power-of-2 scale, then one atomicAdd per block.
__global__ void loss_kernel(const unsigned* __restrict__ hp,
                            const unsigned* __restrict__ maxraw,
                            const unsigned* __restrict__ maxdiff,
                            float* __restrict__ out) {
    __shared__ float tP[256], tG[256];
    int blk = blockIdx.x;
    int b = blk & 15, chunk = (blk >> 4) & 15, plane = blk >> 8;
    const unsigned* P = hp + ((plane * 32 + b) << 16) + (chunk << 12);
    const unsigned* G = P + (16 << 16);
    float c = 0.2f * __uint_as_float(maxdiff[plane]);
    float nP = fminf((float)maxraw[plane * 32 + b], 100.0f);
    float nG = fminf((float)maxraw[plane * 32 + 16 + b], 100.0f);
    const int tid = threadIdx.x;
    tP[tid] = fminf((float)tid, 100.0f) / nP;
    tG[tid] = fminf((float)tid, 100.0f) / nG;
    __syncthreads();
    float acc = 0.0f;
    #pragma unroll
    for (int k = 0; k < 4; ++k) {
        uint4 wp = *(const uint4*)&P[(k << 10) + (tid << 2)];
        uint4 wg = *(const uint4*)&G[(k << 10) + (tid << 2)];
        #pragma unroll
        for (int w = 0; w < 4; ++w) {
            unsigned up = (&wp.x)[w], ug = (&wg.x)[w];
            #pragma unroll
            for (int s = 0; s < 32; s += 8) {
                float pn = tP[(up >> s) & 255u];
                float gn = tG[(ug >> s) & 255u];
                float d = fabsf(pn - gn);
                acc += (d <= c) ? d : (d * d + c * c) / (2.0f * c);
            }
        }
    }
    acc = blockSumF(acc);
    if (threadIdx.x == 0) atomicAdd(out, acc / 4194304.0f);
}

extern "C" void kernel_launch(void* const* d_in, const int* in_sizes, int n_in,
                              void* d_out, int out_size, void* d_ws, size_t ws_size,
                              hipStream_t stream) {
    const float* pred = (const float*)d_in[0];
    const float* gt   = (const float*)d_in[1];
    float* out        = (float*)d_out;
    char* ws          = (char*)d_ws;

    float* tbl        = (float*)ws;
    unsigned* maxz    = (unsigned*)(ws + MAXZ_OFF_B);
    unsigned* maxraw  = maxz;
    unsigned* maxdiff = maxz + 96;
    unsigned* hp      = (unsigned*)(ws + HIST_OFF_B);
    unsigned short* buck = (unsigned short*)(ws + BUCK_OFF_B);

    trig_kernel<<<6, 256, 0, stream>>>(tbl, maxz, out);
    bin_kernel<<<4096, 256, 0, stream>>>(pred, gt, tbl, buck);
    scan_kernel<<<768, 1024, 0, stream>>>(buck, hp, maxraw);
    maxdiff_kernel<<<768, 256, 0, stream>>>(hp, maxraw, maxdiff);
    loss_kernel<<<768, 256, 0, stream>>>(hp, maxraw, maxdiff, out);
}

// Round 13
// 180.243 us; speedup vs baseline: 1.7417x; 1.0253x over previous
//
#include <hip/hip_runtime.h>

#define PI_F 3.14159265358979323846f

// ws layout (bytes):
//   0        : trig table — f32 cosphi[1024], sinphi[1024], costh[512],
//              sinth[512] = 12288 B (written by trig_kernel, read by bin)
//   24576    : maxz — u32 maxraw[3*32] then maxdiff[3] (zeroed by trig blk 0)
//   32768    : packed hist u8: 3 planes × 32 hists × 262144 bins = 24 MB
//   25198592 : bucket regions: 4096 bin-blocks × 24640 B each
//              (64 B header: u16 off[25]; 24576 B data: 12288 u16 in-band ids
//               segmented by bucket = plane*8 + band64)  -> ws end ≈ 126.2 MB
#define MAXZ_OFF_B   24576
#define HIST_OFF_B   32768
#define BUCK_OFF_B   25198592
#define REGION_U16   12320          // region stride in u16 units (24640 B)

// Correctly-rounded a/20000 via Markstein refinement (bit-exact RN).
__device__ inline float div20000(float a) {
    const float r = 1.0f / 20000.0f;
    float q0 = a * r;
    float e = fmaf(-20000.0f, q0, a);
    return fmaf(e, r, q0);
}

__device__ inline int bin1(float v) {
    float f = rintf(div20000(v + 10000.0f) * 512.0f);
    return (int)fminf(fmaxf(f, 0.0f), 511.0f);
}

// Pass 0: compute the 1024 phi + 512 theta sin/cos pairs ONCE. Identical FP
// expressions to the original -> bit-identical values (verified absmax 0).
// Block 0 also zeroes maxz + out.
__global__ __launch_bounds__(256) void trig_kernel(
    float* __restrict__ tbl, unsigned* __restrict__ maxz,
    float* __restrict__ out) {
    const int t = threadIdx.x + blockIdx.x * 256;
    if (blockIdx.x == 0) {
        if (threadIdx.x < 128) maxz[threadIdx.x] = 0u;
        if (threadIdx.x == 128) out[0] = 0.0f;
    }
    if (t < 1024) {
        float fj = (float)t;
        float phi = PI_F * ((2.0f * fj) / 1023.0f - 1.0f);
        tbl[t] = cosf(phi);
        tbl[1024 + t] = sinf(phi);
    } else {
        int i = t - 1024;                       // < 512
        float fi = (float)i;
        float theta = -PI_F * (fi / 511.0f - 0.5f);
        tbl[2048 + i] = cosf(theta);
        tbl[2560 + i] = sinf(theta);
    }
}

// Pass 1: round-9 dual-pass bucket sort with 16× REPLICATED counters,
// stride 17. The dual-pass design no longer packs ranks into item words, so
// replica count is unconstrained: 16 reps shrink the same-word collision
// group from 8 lanes to 4 (SQ_LDS_BANK_CONFLICT was 10.07M ≈ 16 µs of LDS
// serialization in a 51 µs kernel). Stride 17 (coprime to 32) makes the
// 16-iteration prefix loop bank-conflict-free (17t mod 32 distinct across
// threads) — the r5 regression came from the (b<<5)|r layout, not
// replication itself. Counts exact, ranks nondeterministic -> downstream
// bit-identical.
// 4096 blocks = (xcd[0:2], i4[3:9], hh[10:11]), XCD-pinned (wg&7==h&7).
__global__ __launch_bounds__(256) void bin_kernel(
    const float* __restrict__ pred, const float* __restrict__ gt,
    const float* __restrict__ tbl, unsigned short* __restrict__ buck) {
    __shared__ unsigned cnt[408];               // 24 buckets × stride 17
    __shared__ unsigned bsum[24];
    __shared__ unsigned off[25];
    __shared__ __align__(16) unsigned short sdata[12288];
    const int tid = threadIdx.x, wg = blockIdx.x;
    const unsigned rep = (unsigned)(tid & 15);
    const int xcd = wg & 7, i4 = (wg >> 3) & 127, hh = wg >> 10;
    const int h = (hh << 3) | xcd;
    #pragma unroll
    for (int z = 0; z < 2; ++z) {
        int idx = tid + (z << 8);
        if (idx < 408) cnt[idx] = 0u;
    }
    const float4 cp4 = *(const float4*)&tbl[tid << 2];          // cos phi
    const float4 sp4 = *(const float4*)&tbl[1024 + (tid << 2)]; // sin phi
    const float4 ct4 = *(const float4*)&tbl[2048 + (i4 << 2)];  // cos theta
    const float4 st4 = *(const float4*)&tbl[2560 + (i4 << 2)];  // sin theta
    __syncthreads();
    const float* img = ((h >> 4) ? gt : pred) + ((h & 15) << 19);
    // load all 4 rows up-front; kept live across both passes (16 VGPR)
    float4 d4s[4];
    #pragma unroll
    for (int r = 0; r < 4; ++r)
        d4s[r] = *(const float4*)(img + ((i4 * 4 + r) << 10) + (tid << 2));

    // ---- PASS A: count (iB, iC only; plane-1 counts stand in for plane-2)
    #pragma unroll
    for (int r = 0; r < 4; ++r) {
        const float ct = (&ct4.x)[r], st = (&st4.x)[r];
        #pragma unroll
        for (int k = 0; k < 4; ++k) {
            float d = (&d4s[r].x)[k];
            float aB = (&sp4.x)[k] * ct;        // identical op order
            float B = (d * aB) * 1000.0f;
            float C = (d * (-st)) * 1000.0f;
            int iB = bin1(B), iC = bin1(C);
            atomicAdd(&cnt[(unsigned)(iB >> 6) * 17u + rep], 1u);
            atomicAdd(&cnt[(8u + (unsigned)(iC >> 6)) * 17u + rep], 1u);
        }
    }
    __syncthreads();
    // replica exclusive-prefix in place for buckets 0..15 (conflict-free:
    // addresses 17*tid+r hit distinct banks across tid for fixed r)
    if (tid < 16) {
        unsigned s = 0;
        #pragma unroll
        for (int r = 0; r < 16; ++r) {
            unsigned t = cnt[tid * 17 + r];
            cnt[tid * 17 + r] = s;
            s += t;
        }
        bsum[tid] = s;
    }
    __syncthreads();
    // buckets 16..23 mirror 8..15 (identical counts, keyed on iC>>6)
    if (tid >= 16 && tid < 24) {
        #pragma unroll
        for (int r = 0; r < 16; ++r)
            cnt[tid * 17 + r] = cnt[(tid - 8) * 17 + r];
        bsum[tid] = bsum[tid - 8];
    }
    __syncthreads();
    if (tid == 0) {
        unsigned s = 0;
        #pragma unroll
        for (int b = 0; b < 24; ++b) { off[b] = s; s += bsum[b]; }
        off[24] = s;                            // == 12288
    }
    __syncthreads();
    if (tid < 24) {
        unsigned o = off[tid];
        #pragma unroll
        for (int r = 0; r < 16; ++r) cnt[tid * 17 + r] += o;
    }
    __syncthreads();

    // ---- PASS B: recompute + rank-scatter into LDS staging
    #pragma unroll
    for (int r = 0; r < 4; ++r) {
        const float ct = (&ct4.x)[r], st = (&st4.x)[r];
        #pragma unroll
        for (int k = 0; k < 4; ++k) {
            float d = (&d4s[r].x)[k];
            float aA = (&cp4.x)[k] * ct;        // identical op order to r3/r5
            float aB = (&sp4.x)[k] * ct;
            float A = (d * aA) * 1000.0f;
            float B = (d * aB) * 1000.0f;
            float C = (d * (-st)) * 1000.0f;
            int iA = bin1(A), iB = bin1(B), iC = bin1(C);
            // plane0: y=iB,x=iA; plane1: y=iC,x=iA; plane2: y=iC,x=iB
            unsigned f0 = ((unsigned)iB << 9) | (unsigned)iA;
            unsigned f1 = ((unsigned)iC << 9) | (unsigned)iA;
            unsigned f2 = ((unsigned)iC << 9) | (unsigned)iB;
            unsigned b0 = f0 >> 15;             // iB>>6
            unsigned bc = f1 >> 15;             // iC>>6
            unsigned p0 = atomicAdd(&cnt[b0 * 17u + rep], 1u);
            sdata[p0] = (unsigned short)(f0 & 32767u);
            unsigned p1 = atomicAdd(&cnt[(8u + bc) * 17u + rep], 1u);
            sdata[p1] = (unsigned short)(f1 & 32767u);
            unsigned p2 = atomicAdd(&cnt[(16u + bc) * 17u + rep], 1u);
            sdata[p2] = (unsigned short)(f2 & 32767u);
        }
    }
    __syncthreads();
    unsigned short* regG = buck + (size_t)wg * REGION_U16;
    if (tid < 25) regG[tid] = (unsigned short)off[tid];
    // coalesced copy-out: 12288 u16 = 1536 uint4 = 6 per thread exactly
    const uint4* s4p = (const uint4*)sdata;
    uint4* g4 = (uint4*)(regG + 32);            // data after 64 B header
    #pragma unroll
    for (int c = 0; c < 6; ++c) g4[(c << 8) + tid] = s4p[(c << 8) + tid];
}

// Pass 2: round-11 structure (hoisted headers, verified) + 2-way unroll of
// the segment uint4 loop. Typical segments are nv<=64 (one uint4/lane, the
// unrolled path never taken); hot center segments run nv=128-512 where the
// serial load->atomic chain now has two loads in flight. Pure reorder,
// counts exact -> bit-identical hists.
// WG = (plane, h, band); 1024 threads, 2 blocks/CU = 32 waves/CU.
// blockIdx bits: [0:2]=xcd==h&7 (L2 pin), [3:4]=h>>3, [5:9]=X (LPT order).
__global__ __launch_bounds__(1024, 8) void scan_kernel(
    const unsigned short* __restrict__ buck, unsigned* __restrict__ hp,
    unsigned* __restrict__ maxraw) {
    __shared__ unsigned lh[16384];              // 64 rows × 512 bins, u16×2
    __shared__ unsigned s4[16];
    const int tid = threadIdx.x, wg = blockIdx.x;
    const int xcd = wg & 7, hhi = (wg >> 3) & 3;
    const int X = wg >> 5;                      // 0..23
    const int pair = X / 6, idx6 = X % 6;
    const int plane = idx6 >> 1;
    const int band = (idx6 & 1) ? (4 + pair) : (3 - pair);
    const int h = (hhi << 3) | xcd;
    const int bucket = plane * 8 + band;

    #pragma unroll
    for (int k = 0; k < 4; ++k)
        *(uint4*)&lh[(k << 12) + (tid << 2)] = make_uint4(0, 0, 0, 0);
    __syncthreads();

    const int wid = tid >> 6, lane = tid & 63;
    // hoist all 8 region headers (layout: reg[b] == off[b], b=0..24)
    int lo[8], hi[8];
    #pragma unroll
    for (int j = 0; j < 8; ++j) {
        const unsigned short* reg = buck +
            (size_t)(xcd | ((wid + (j << 4)) << 3) | (hhi << 10)) * REGION_U16;
        lo[j] = reg[bucket];
        hi[j] = reg[bucket + 1];
    }
    auto process = [&](uint4 w) {
        #pragma unroll
        for (int q = 0; q < 4; ++q) {
            const unsigned u = (&w.x)[q];
            const unsigned idl = u & 65535u, idh = u >> 16;
            atomicAdd(&lh[idl >> 1], 1u << ((idl & 1u) << 4));
            atomicAdd(&lh[idh >> 1], 1u << ((idh & 1u) << 4));
        }
    };
    #pragma unroll
    for (int j = 0; j < 8; ++j) {
        const unsigned short* data = buck +
            (size_t)(xcd | ((wid + (j << 4)) << 3) | (hhi << 10)) * REGION_U16
            + 32;
        int a = (lo[j] + 7) & ~7;               // first 16B-aligned index
        if (a > hi[j]) a = hi[j];
        const int head = a - lo[j];             // <= 7
        if (lane < head) {
            const unsigned id = data[lo[j] + lane];
            atomicAdd(&lh[id >> 1], 1u << ((id & 1u) << 4));
        }
        const int nv = (hi[j] - a) >> 3;        // full uint4 groups
        int v = lane;
        for (; v + 64 < nv; v += 128) {         // hot segments: 2 loads in flight
            const uint4 w0 = *(const uint4*)&data[a + (v << 3)];
            const uint4 w1 = *(const uint4*)&data[a + ((v + 64) << 3)];
            process(w0);
            process(w1);
        }
        if (v < nv) {
            const uint4 w = *(const uint4*)&data[a + (v << 3)];
            process(w);
        }
        const int tail = (hi[j] - a) & 7;       // <= 7
        if (lane < tail) {
            const unsigned id = data[a + (nv << 3) + lane];
            atomicAdd(&lh[id >> 1], 1u << ((id & 1u) << 4));
        }
    }
    __syncthreads();

    // pack to u8 (sat 255; downstream clamps at 100) + raw band max
    unsigned m = 0;
    unsigned* gout = hp + ((plane * 32 + h) << 16) + (band << 13);
    #pragma unroll
    for (int k = 0; k < 8; ++k) {
        int w = (k << 10) + tid;
        unsigned v0 = lh[2 * w], v1 = lh[2 * w + 1];
        unsigned c0 = v0 & 65535u, c1 = v0 >> 16;
        unsigned c2 = v1 & 65535u, c3 = v1 >> 16;
        m = max(max(m, max(c0, c1)), max(c2, c3));
        gout[w] = min(c0, 255u) | (min(c1, 255u) << 8) |
                  (min(c2, 255u) << 16) | (min(c3, 255u) << 24);
    }
    #pragma unroll
    for (int o = 32; o; o >>= 1) m = max(m, (unsigned)__shfl_down((int)m, o));
    if ((tid & 63) == 0) s4[tid >> 6] = m;
    __syncthreads();
    if (tid == 0) {
        #pragma unroll
        for (int k = 1; k < 16; ++k) m = max(m, s4[k]);
        atomicMax(&maxraw[plane * 32 + h], m);
    }
}

__device__ inline float blockMaxF(float v) {
    #pragma unroll
    for (int o = 32; o; o >>= 1) v = fmaxf(v, __shfl_down(v, o));
    __shared__ float s[4];
    if ((threadIdx.x & 63) == 0) s[threadIdx.x >> 6] = v;
    __syncthreads();
    if (threadIdx.x == 0) v = fmaxf(fmaxf(s[0], s[1]), fmaxf(s[2], s[3]));
    return v;
}

__device__ inline float blockSumF(float v) {
    #pragma unroll
    for (int o = 32; o; o >>= 1) v += __shfl_down(v, o);
    __shared__ float s[4];
    if ((threadIdx.x & 63) == 0) s[threadIdx.x >> 6] = v;
    __syncthreads();
    if (threadIdx.x == 0) v = (s[0] + s[1]) + (s[2] + s[3]);
    return v;
}

// 768 blocks = 3 planes × 16 b × 16 chunks; uint4 loads. nP/nG are
// block-uniform, so min(v,100)/n over the 256 byte values is precomputed
// into 256-entry LDS tables (bit-identical values).
__global__ void maxdiff_kernel(const unsigned* __restrict__ hp,
                               const unsigned* __restrict__ maxraw,
                               unsigned* __restrict__ maxdiff) {
    __shared__ float tP[256], tG[256];
    int blk = blockIdx.x;
    int b = blk & 15, chunk = (blk >> 4) & 15, plane = blk >> 8;
    const unsigned* P = hp + ((plane * 32 + b) << 16) + (chunk << 12);
    const unsigned* G = P + (16 << 16);
    float nP = fminf((float)maxraw[plane * 32 + b], 100.0f);
    float nG = fminf((float)maxraw[plane * 32 + 16 + b], 100.0f);
    const int tid = threadIdx.x;
    tP[tid] = fminf((float)tid, 100.0f) / nP;
    tG[tid] = fminf((float)tid, 100.0f) / nG;
    __syncthreads();
    float m = 0.0f;
    #pragma unroll
    for (int k = 0; k < 4; ++k) {
        uint4 wp = *(const uint4*)&P[(k << 10) + (tid << 2)];
        uint4 wg = *(const uint4*)&G[(k << 10) + (tid << 2)];
        #pragma unroll
        for (int w = 0; w < 4; ++w) {
            unsigned up = (&wp.x)[w], ug = (&wg.x)[w];
            #pragma unroll
            for (int s = 0; s < 32; s += 8) {
                float pn = tP[(up >> s) & 255u];
                float gn = tG[(ug >> s) & 255u];
                m = fmaxf(m, fabsf(pn - gn));
            }
        }
    }
    m = blockMaxF(m);
    if (threadIdx.x == 0) atomicMax(&maxdiff[plane], __float_as_uint(m));
}

// Accumulates directly into out[0] (pre-zeroed by trig block 0):
// blocksum/2^22 is an exact power-of-2 scale, then one atomicAdd per block.
__global__ void loss_kernel(const unsigned* __restrict__ hp,
                            const unsigned* __restrict__ maxraw,
                            const unsigned* __restrict__ maxdiff,
                            float* __restrict__ out) {
    __shared__ float tP[256], tG[256];
    int blk = blockIdx.x;
    int b = blk & 15, chunk = (blk >> 4) & 15, plane = blk >> 8;
    const unsigned* P = hp + ((plane * 32 + b) << 16) + (chunk << 12);
    const unsigned* G = P + (16 << 16);
    float c = 0.2f * __uint_as_float(maxdiff[plane]);
    float nP = fminf((float)maxraw[plane * 32 + b], 100.0f);
    float nG = fminf((float)maxraw[plane * 32 + 16 + b], 100.0f);
    const int tid = threadIdx.x;
    tP[tid] = fminf((float)tid, 100.0f) / nP;
    tG[tid] = fminf((float)tid, 100.0f) / nG;
    __syncthreads();
    float acc = 0.0f;
    #pragma unroll
    for (int k = 0; k < 4; ++k) {
        uint4 wp = *(const uint4*)&P[(k << 10) + (tid << 2)];
        uint4 wg = *(const uint4*)&G[(k << 10) + (tid << 2)];
        #pragma unroll
        for (int w = 0; w < 4; ++w) {
            unsigned up = (&wp.x)[w], ug = (&wg.x)[w];
            #pragma unroll
            for (int s = 0; s < 32; s += 8) {
                float pn = tP[(up >> s) & 255u];
                float gn = tG[(ug >> s) & 255u];
                float d = fabsf(pn - gn);
                acc += (d <= c) ? d : (d * d + c * c) / (2.0f * c);
            }
        }
    }
    acc = blockSumF(acc);
    if (threadIdx.x == 0) atomicAdd(out, acc / 4194304.0f);
}

extern "C" void kernel_launch(void* const* d_in, const int* in_sizes, int n_in,
                              void* d_out, int out_size, void* d_ws, size_t ws_size,
                              hipStream_t stream) {
    const float* pred = (const float*)d_in[0];
    const float* gt   = (const float*)d_in[1];
    float* out        = (float*)d_out;
    char* ws          = (char*)d_ws;

    float* tbl        = (float*)ws;
    unsigned* maxz    = (unsigned*)(ws + MAXZ_OFF_B);
    unsigned* maxraw  = maxz;
    unsigned* maxdiff = maxz + 96;
    unsigned* hp      = (unsigned*)(ws + HIST_OFF_B);
    unsigned short* buck = (unsigned short*)(ws + BUCK_OFF_B);

    trig_kernel<<<6, 256, 0, stream>>>(tbl, maxz, out);
    bin_kernel<<<4096, 256, 0, stream>>>(pred, gt, tbl, buck);
    scan_kernel<<<768, 1024, 0, stream>>>(buck, hp, maxraw);
    maxdiff_kernel<<<768, 256, 0, stream>>>(hp, maxraw, maxdiff);
    loss_kernel<<<768, 256, 0, stream>>>(hp, maxraw, maxdiff, out);
}